// Round 2
// baseline (807.280 us; speedup 1.0000x reference)
//
#include <hip/hip_runtime.h>
#include <hip/hip_bf16.h>
#include <cstdint>
#include <cstddef>

using bf16 = __hip_bfloat16;
using short8 = __attribute__((ext_vector_type(8))) short;   // 8 bf16 (4 VGPRs)
using floatx4 = __attribute__((ext_vector_type(4))) float;  // MFMA C/D frag

#define MFMA_BF16(A, B, C) __builtin_amdgcn_mfma_f32_16x16x32_bf16((A), (B), (C), 0, 0, 0)

__device__ inline short bf16_bits(float x) {
  bf16 v = __float2bfloat16(x);
  short r;
  __builtin_memcpy(&r, &v, 2);
  return r;
}

// load 8 consecutive elements as bf16 bits (converting if the source is f32)
__device__ inline short8 load8(const bf16* p) { return *(const short8*)p; }
__device__ inline short8 load8(const float* p) {
  const float4 a = *(const float4*)p;
  const float4 b = *(const float4*)(p + 4);
  short8 r;
  r[0] = bf16_bits(a.x); r[1] = bf16_bits(a.y); r[2] = bf16_bits(a.z); r[3] = bf16_bits(a.w);
  r[4] = bf16_bits(b.x); r[5] = bf16_bits(b.y); r[6] = bf16_bits(b.z); r[7] = bf16_bits(b.w);
  return r;
}

__device__ inline void store_c(bf16* p, float v) { *p = __float2bfloat16(v); }
__device__ inline void store_c(float* p, float v) { *p = v; }

// ---------------------------------------------------------------------------
// GEMM: C[m,n] = sum_k A[m,k] * B[n,k]; A is MxK row-major, B is NxK row-major.
// Inputs converted to bf16 at staging; fp32 MFMA accumulation. Tile 128x128,
// BK=64. 256 threads = 4 waves (2x2), each wave 64x64 via 4x4 MFMA 16x16x32.
// LDS layout fragment-contiguous: [k/8][row][8] so frag loads are ds_read_b128.
// ---------------------------------------------------------------------------
template <typename TA, typename TB, typename TC>
__global__ __launch_bounds__(256) void gemm_bt(
    const TA* __restrict__ A, const TB* __restrict__ B, TC* __restrict__ C,
    int M, int N, int K) {
  __shared__ short As[8 * 128 * 8];  // [ko][m][8]
  __shared__ short Bs[8 * 128 * 8];  // [ko][n][8]
  const int tid = threadIdx.x;
  const int wave = tid >> 6;
  const int lane = tid & 63;
  const int lrow = lane & 15;
  const int quad = lane >> 4;
  const int wm = (wave >> 1) * 64;
  const int wn = (wave & 1) * 64;
  const int tm = blockIdx.y * 128;
  const int tn = blockIdx.x * 128;

  // staging map: 2 threads per row, each covers 32 consecutive k elements
  const int sr = tid >> 1;  // row 0..127 of the tile
  const int sh = tid & 1;   // which 32-element half of the 64-wide k strip
  const TA* Ap = A + (size_t)(tm + sr) * K + sh * 32;
  const TB* Bp = B + (size_t)(tn + sr) * K + sh * 32;

  floatx4 acc[4][4] = {};
  short8 av[4], bv[4];
#pragma unroll
  for (int j = 0; j < 4; ++j) {
    av[j] = load8(Ap + j * 8);
    bv[j] = load8(Bp + j * 8);
  }

  for (int k0 = 0; k0 < K; k0 += 64) {
    __syncthreads();
#pragma unroll
    for (int j = 0; j < 4; ++j) {
      *(short8*)&As[((sh * 4 + j) * 128 + sr) * 8] = av[j];
      *(short8*)&Bs[((sh * 4 + j) * 128 + sr) * 8] = bv[j];
    }
    __syncthreads();
    if (k0 + 64 < K) {  // prefetch next tile into registers while MFMA runs
#pragma unroll
      for (int j = 0; j < 4; ++j) {
        av[j] = load8(Ap + k0 + 64 + j * 8);
        bv[j] = load8(Bp + k0 + 64 + j * 8);
      }
    }
#pragma unroll
    for (int kk = 0; kk < 2; ++kk) {
      short8 af[4], bfr[4];
#pragma unroll
      for (int i = 0; i < 4; ++i) {
        af[i] = *(const short8*)&As[((kk * 4 + quad) * 128 + wm + i * 16 + lrow) * 8];
        bfr[i] = *(const short8*)&Bs[((kk * 4 + quad) * 128 + wn + i * 16 + lrow) * 8];
      }
#pragma unroll
      for (int i = 0; i < 4; ++i)
#pragma unroll
        for (int j = 0; j < 4; ++j)
          acc[i][j] = MFMA_BF16(af[i], bfr[j], acc[i][j]);
    }
  }

  // epilogue: C/D layout col=lane&15, row=quad*4+reg (m89-verified)
#pragma unroll
  for (int i = 0; i < 4; ++i)
#pragma unroll
    for (int j = 0; j < 4; ++j)
#pragma unroll
      for (int r = 0; r < 4; ++r) {
        const int row = tm + wm + i * 16 + quad * 4 + r;
        const int col = tn + wn + j * 16 + lrow;
        store_c(&C[(size_t)row * N + col], acc[i][j][r]);
      }
}

// ---------------------------------------------------------------------------
// RoPE, in-place on the bf16 qkv buffer. qkv[b,s,f], f = (h/2)*768 + (h&1)*128
// + {q:0,k:256,v:512} + d. Rotate interleaved pairs of the first 32 dims of
// q,k. One thread per (b,s,h,q/k,pair): 4096*16*2*16 = 8192*256 threads.
// ---------------------------------------------------------------------------
__global__ void rope_kernel(bf16* __restrict__ qkv) {
  const int idx = blockIdx.x * 256 + threadIdx.x;
  const int i = idx & 15;  // freq/pair index
  int t = idx >> 4;
  const int qk = t & 1;
  t >>= 1;
  const int h = t & 15;
  t >>= 4;  // t = b*2048 + s
  const int s = t & 2047;
  bf16* p = qkv + (size_t)t * 6144 + (h >> 1) * 768 + (h & 1) * 128 + qk * 256 + 2 * i;
  const float x0 = __bfloat162float(p[0]);
  const float x1 = __bfloat162float(p[1]);
  const float inv = powf(10000.f, -(float)(2 * i) / 32.f);
  const float ang = (float)s * inv;
  float sn, cs;
  sincosf(ang, &sn, &cs);
  p[0] = __float2bfloat16(x0 * cs - x1 * sn);
  p[1] = __float2bfloat16(x1 * cs + x0 * sn);
}

// ---------------------------------------------------------------------------
// Flash attention. Grid (S/128, H, B). Block 256 = 4 waves; wave w owns q-rows
// [w*32, w*32+32). Q held in registers as A-frags; per k-block (64 keys):
// stage K (B-frag layout) and V transposed (B-frag layout) in LDS, S = Q K^T
// via MFMA, scale+causal mask, online softmax (16-lane shuffle reductions over
// the C-layout row groups), P -> LDS (A-frag layout), O += P V via MFMA.
// ---------------------------------------------------------------------------
__global__ __launch_bounds__(256) void attn_flash(
    const bf16* __restrict__ qkv, bf16* __restrict__ out) {
  __shared__ short Ks[16 * 64 * 8];  // [d/8][sk][8]
  __shared__ short Vs[8 * 128 * 8];  // [sk/8][d][8]   (V transposed)
  __shared__ short Ps[8 * 128 * 8];  // [sk/8][qrow][8]
  const int tid = threadIdx.x;
  const int wave = tid >> 6;
  const int lane = tid & 63;
  const int lrow = lane & 15;
  const int quad = lane >> 4;
  const int qb = blockIdx.x;
  const int h = blockIdx.y;
  const int b = blockIdx.z;
  const size_t SROW = 6144;
  const bf16* base = qkv + (size_t)b * 2048 * SROW;
  const int qoff = (h >> 1) * 768 + (h & 1) * 128;
  const int koff = qoff + 256;
  const int voff = qoff + 512;
  const float scale = 0.088388347648318447f;  // 1/sqrt(128)

  // Q A-frags: rows wave*32 + rt*16 + (lane&15), k(d) = ks*32 + quad*8 + j
  short8 qf[2][4];
#pragma unroll
  for (int rt = 0; rt < 2; ++rt) {
    const bf16* qp =
        base + (size_t)(qb * 128 + wave * 32 + rt * 16 + lrow) * SROW + qoff + quad * 8;
#pragma unroll
    for (int ks = 0; ks < 4; ++ks) qf[rt][ks] = *(const short8*)(qp + ks * 32);
  }

  floatx4 o[2][8] = {};
  float m_i[8], l_i[8];
#pragma unroll
  for (int i = 0; i < 8; ++i) {
    m_i[i] = -1e30f;
    l_i[i] = 0.f;
  }

  const int sr = tid >> 2;  // staging row 0..63
  const int sq = tid & 3;   // staging quarter of the 128-wide d strip

  const int kb_end = qb * 2 + 2;  // causal: only k-blocks overlapping tril
  for (int kb = 0; kb < kb_end; ++kb) {
    __syncthreads();  // all waves done reading Ks/Vs from previous iteration
    {
      // K tile: 64 rows x 128 d -> Ks[d/8][sk][8]
      const bf16* kp = base + (size_t)(kb * 64 + sr) * SROW + koff + sq * 32;
      short8 kv[4];
#pragma unroll
      for (int j = 0; j < 4; ++j) kv[j] = *(const short8*)(kp + j * 8);
#pragma unroll
      for (int j = 0; j < 4; ++j) *(short8*)&Ks[((sq * 4 + j) * 64 + sr) * 8] = kv[j];

      // V tile transposed: load V[sk][d0..d0+7] coalesced, scatter to Vs[sk/8][d][sk%8]
      const bf16* vp = base + (size_t)(kb * 64 + sr) * SROW + voff + sq * 8;
      const int so = (sr >> 3) * 128, si = sr & 7;
#pragma unroll
      for (int i = 0; i < 4; ++i) {
        short8 vv = *(const short8*)(vp + i * 32);
        const int d0 = sq * 8 + i * 32;
#pragma unroll
        for (int j = 0; j < 8; ++j) Vs[(so + d0 + j) * 8 + si] = vv[j];
      }
    }
    __syncthreads();

    // S = Q K^T  (rows: wave's 32 q-rows; cols: 64 keys)
    floatx4 sc[2][4] = {};
#pragma unroll
    for (int ks = 0; ks < 4; ++ks) {
      short8 bfr[4];
#pragma unroll
      for (int ct = 0; ct < 4; ++ct)
        bfr[ct] = *(const short8*)&Ks[((ks * 4 + quad) * 64 + ct * 16 + lrow) * 8];
#pragma unroll
      for (int rt = 0; rt < 2; ++rt)
#pragma unroll
        for (int ct = 0; ct < 4; ++ct)
          sc[rt][ct] = MFMA_BF16(qf[rt][ks], bfr[ct], sc[rt][ct]);
    }

    // scale + causal mask + online softmax (per C-layout row)
#pragma unroll
    for (int rt = 0; rt < 2; ++rt)
#pragma unroll
      for (int r = 0; r < 4; ++r) {
        const int idx = rt * 4 + r;
        const int row_g = qb * 128 + wave * 32 + rt * 16 + quad * 4 + r;
        float mx = -1e30f;
#pragma unroll
        for (int ct = 0; ct < 4; ++ct) {
          const int col_g = kb * 64 + ct * 16 + lrow;
          float v = sc[rt][ct][r] * scale;
          if (col_g > row_g) v = -1e9f;
          sc[rt][ct][r] = v;
          mx = fmaxf(mx, v);
        }
#pragma unroll
        for (int off = 1; off < 16; off <<= 1) mx = fmaxf(mx, __shfl_xor(mx, off, 64));
        const float mnew = fmaxf(m_i[idx], mx);
        const float alpha = __expf(m_i[idx] - mnew);
        m_i[idx] = mnew;
        float rs = 0.f;
#pragma unroll
        for (int ct = 0; ct < 4; ++ct) {
          const float p = __expf(sc[rt][ct][r] - mnew);
          sc[rt][ct][r] = p;
          rs += p;
        }
#pragma unroll
        for (int off = 1; off < 16; off <<= 1) rs += __shfl_xor(rs, off, 64);
        l_i[idx] = l_i[idx] * alpha + rs;
#pragma unroll
        for (int dt = 0; dt < 8; ++dt) o[rt][dt][r] *= alpha;
      }

    // P (bf16) -> LDS in A-frag layout
#pragma unroll
    for (int rt = 0; rt < 2; ++rt)
#pragma unroll
      for (int ct = 0; ct < 4; ++ct)
#pragma unroll
        for (int r = 0; r < 4; ++r) {
          const int row_l = wave * 32 + rt * 16 + quad * 4 + r;
          const int sk = ct * 16 + lrow;
          Ps[((sk >> 3) * 128 + row_l) * 8 + (sk & 7)] = bf16_bits(sc[rt][ct][r]);
        }
    __syncthreads();

    // O += P V
#pragma unroll
    for (int ks = 0; ks < 2; ++ks) {
      short8 af[2], bfr[8];
#pragma unroll
      for (int rt = 0; rt < 2; ++rt)
        af[rt] = *(const short8*)&Ps[((ks * 4 + quad) * 128 + wave * 32 + rt * 16 + lrow) * 8];
#pragma unroll
      for (int dt = 0; dt < 8; ++dt)
        bfr[dt] = *(const short8*)&Vs[((ks * 4 + quad) * 128 + dt * 16 + lrow) * 8];
#pragma unroll
      for (int rt = 0; rt < 2; ++rt)
#pragma unroll
        for (int dt = 0; dt < 8; ++dt)
          o[rt][dt] = MFMA_BF16(af[rt], bfr[dt], o[rt][dt]);
    }
  }

  // epilogue: O / l, store to (b, s, h*128 + d) bf16
#pragma unroll
  for (int rt = 0; rt < 2; ++rt)
#pragma unroll
    for (int dt = 0; dt < 8; ++dt)
#pragma unroll
      for (int r = 0; r < 4; ++r) {
        const int row = qb * 128 + wave * 32 + rt * 16 + quad * 4 + r;
        const int d = dt * 16 + lrow;
        const float val = o[rt][dt][r] / l_i[rt * 4 + r];
        out[((size_t)(b * 2048 + row)) * 2048 + h * 128 + d] = __float2bfloat16(val);
      }
}

// ---------------------------------------------------------------------------
extern "C" void kernel_launch(void* const* d_in, const int* in_sizes, int n_in,
                              void* d_out, int out_size, void* d_ws, size_t ws_size,
                              hipStream_t stream) {
  const float* hidden = (const float*)d_in[0];  // (2,2048,2048) f32
  const float* Wqkv = (const float*)d_in[1];    // (6144,2048)  f32
  const float* Wout = (const float*)d_in[2];    // (2048,2048)  f32
  float* outp = (float*)d_out;                  // (2,2048,2048) f32

  bf16* qkv = (bf16*)d_ws;                    // 4096 x 6144 bf16 = 48 MiB
  bf16* attnout = qkv + (size_t)4096 * 6144;  // 4096 x 2048 bf16 = 16 MiB

  // 1) qkv = hidden @ W_qkv^T   (M=4096, N=6144, K=2048), f32 in -> bf16 out
  gemm_bt<float, float, bf16><<<dim3(48, 32), 256, 0, stream>>>(
      hidden, Wqkv, qkv, 4096, 6144, 2048);
  // 2) RoPE in-place on q,k rot dims
  rope_kernel<<<8192, 256, 0, stream>>>(qkv);
  // 3) causal flash attention -> attnout (b,s,h*128+d) bf16
  attn_flash<<<dim3(16, 16, 2), 256, 0, stream>>>(qkv, attnout);
  // 4) out = attnout @ W_out^T  (M=4096, N=2048, K=2048), bf16 x f32 -> f32
  gemm_bt<bf16, float, float><<<dim3(16, 32), 256, 0, stream>>>(
      attnout, Wout, outp, 4096, 2048, 2048);
}

// Round 4
// 545.200 us; speedup vs baseline: 1.4807x; 1.4807x over previous
//
#include <hip/hip_runtime.h>
#include <hip/hip_bf16.h>
#include <cstdint>
#include <cstddef>

using bf16 = __hip_bfloat16;
using short4v = __attribute__((ext_vector_type(4))) short;  // 4 bf16 (2 VGPRs)
using short8 = __attribute__((ext_vector_type(8))) short;   // 8 bf16 (4 VGPRs)
using floatx4 = __attribute__((ext_vector_type(4))) float;  // MFMA C/D frag

#define MFMA_BF16(A, B, C) __builtin_amdgcn_mfma_f32_16x16x32_bf16((A), (B), (C), 0, 0, 0)

__device__ inline short bf16_bits(float x) {
  bf16 v = __float2bfloat16(x);
  short r;
  __builtin_memcpy(&r, &v, 2);
  return r;
}

__device__ inline void store_c(bf16* p, float v) { *p = __float2bfloat16(v); }
__device__ inline void store_c(float* p, float v) { *p = v; }

// ---------------------------------------------------------------------------
// f32 -> bf16 bulk convert (RNE). 8 elements/thread, 16B stores.
// ---------------------------------------------------------------------------
__global__ __launch_bounds__(256) void f32_to_bf16_kernel(
    const float* __restrict__ src, bf16* __restrict__ dst, int n8) {
  const int i = blockIdx.x * 256 + threadIdx.x;
  if (i >= n8) return;
  const float4 a = ((const float4*)src)[2 * i];
  const float4 b = ((const float4*)src)[2 * i + 1];
  short8 r;
  r[0] = bf16_bits(a.x); r[1] = bf16_bits(a.y); r[2] = bf16_bits(a.z); r[3] = bf16_bits(a.w);
  r[4] = bf16_bits(b.x); r[5] = bf16_bits(b.y); r[6] = bf16_bits(b.z); r[7] = bf16_bits(b.w);
  *(short8*)(dst + (size_t)i * 8) = r;
}

// ---------------------------------------------------------------------------
// GEMM (m97 structure): C[m,n] = sum_k A[m,k]*B[n,k], A,B row-major bf16 with
// row stride K; C row-major stride ldc. Tile 128x128, BK=64, 4 waves (2x2),
// wave does 64x64 via 4x4 MFMA 16x16x32 frags. M = grid.y*128, N = grid.x*128.
// Staging: global_load_lds width=16 (DMA). LDS [row][64] lane-contiguous (DMA
// requirement); the GLOBAL chunk each lane fetches is XOR-swizzled
// (g = c ^ (row&7)) so fragment ds_read_b128s hit all 32 banks evenly.
// ---------------------------------------------------------------------------
template <typename TC>
__global__ __launch_bounds__(256) void gemm_bt_async(
    const bf16* __restrict__ A, const bf16* __restrict__ B, TC* __restrict__ C,
    int ldc, int K) {
  __shared__ bf16 As[128 * 64];
  __shared__ bf16 Bs[128 * 64];
  const int tid = threadIdx.x;
  const int lane = tid & 63;
  const int wave = tid >> 6;
  const int lrow = lane & 15;
  const int quad = lane >> 4;
  const int wm = (wave >> 1) * 64;
  const int wn = (wave & 1) * 64;
  const int tm = blockIdx.y * 128;
  const int tn = blockIdx.x * 128;

  const int srow = tid >> 3;  // 0..31: row within 32-row staging group
  const int scl = tid & 7;    // LDS 16B-chunk index within the row

  floatx4 acc[4][4] = {};

  for (int k0 = 0; k0 < K; k0 += 64) {
    __syncthreads();  // all waves done reading As/Bs from previous iter
#pragma unroll
    for (int r = 0; r < 4; ++r) {
      const int row = r * 32 + srow;
      const int scg = scl ^ (row & 7);  // swizzled global chunk
      __builtin_amdgcn_global_load_lds(
          (const __attribute__((address_space(1))) void*)(A + (size_t)(tm + row) * K + k0 + scg * 8),
          (__attribute__((address_space(3))) void*)(As + row * 64 + scl * 8), 16, 0, 0);
    }
#pragma unroll
    for (int r = 0; r < 4; ++r) {
      const int row = r * 32 + srow;
      const int scg = scl ^ (row & 7);
      __builtin_amdgcn_global_load_lds(
          (const __attribute__((address_space(1))) void*)(B + (size_t)(tn + row) * K + k0 + scg * 8),
          (__attribute__((address_space(3))) void*)(Bs + row * 64 + scl * 8), 16, 0, 0);
    }
    __syncthreads();  // compiler emits vmcnt(0) drain before this barrier

#pragma unroll
    for (int kk = 0; kk < 2; ++kk) {
      short8 af[4], bfr[4];
#pragma unroll
      for (int i = 0; i < 4; ++i) {
        const int ra = wm + i * 16 + lrow;
        const int rb = wn + i * 16 + lrow;
        af[i] = *(const short8*)&As[ra * 64 + (((kk * 4 + quad) ^ (ra & 7)) * 8)];
        bfr[i] = *(const short8*)&Bs[rb * 64 + (((kk * 4 + quad) ^ (rb & 7)) * 8)];
      }
#pragma unroll
      for (int i = 0; i < 4; ++i)
#pragma unroll
        for (int j = 0; j < 4; ++j)
          acc[i][j] = MFMA_BF16(af[i], bfr[j], acc[i][j]);
    }
  }

  // epilogue: C/D layout col=lane&15, row=quad*4+reg (m89-verified)
#pragma unroll
  for (int i = 0; i < 4; ++i)
#pragma unroll
    for (int j = 0; j < 4; ++j)
#pragma unroll
      for (int r = 0; r < 4; ++r) {
        const int row = tm + wm + i * 16 + quad * 4 + r;
        const int col = tn + wn + j * 16 + lrow;
        store_c(&C[(size_t)row * ldc + col], acc[i][j][r]);
      }
}

// ---------------------------------------------------------------------------
// Mixed GEMM for the out-projection: A (bf16, row stride K) staged via
// global_load_lds; B is the ORIGINAL f32 weight (row stride K), staged via
// register prefetch + convert + swizzled ds_write (no bf16 copy of W_out
// needed -> fits the 64 MiB workspace). C f32, stride ldc.
// ---------------------------------------------------------------------------
__global__ __launch_bounds__(256) void gemm_abf16_bf32(
    const bf16* __restrict__ A, const float* __restrict__ B, float* __restrict__ C,
    int ldc, int K) {
  __shared__ bf16 As[128 * 64];
  __shared__ bf16 Bs[128 * 64];
  const int tid = threadIdx.x;
  const int lane = tid & 63;
  const int wave = tid >> 6;
  const int lrow = lane & 15;
  const int quad = lane >> 4;
  const int wm = (wave >> 1) * 64;
  const int wn = (wave & 1) * 64;
  const int tm = blockIdx.y * 128;
  const int tn = blockIdx.x * 128;

  const int srow = tid >> 3;  // A staging: 32-row group row
  const int scl = tid & 7;    // A staging: LDS chunk
  const int c16 = tid & 15;   // B staging: 16B f32 chunk within the 64-col strip
  const int br0 = tid >> 4;   // B staging: base row 0..15 (8 rows, stride 16)

  floatx4 acc[4][4] = {};
  float4 breg[8];
#pragma unroll
  for (int r = 0; r < 8; ++r)
    breg[r] = *(const float4*)(B + (size_t)(tn + r * 16 + br0) * K + c16 * 4);

  for (int k0 = 0; k0 < K; k0 += 64) {
    __syncthreads();  // all waves done reading As/Bs from previous iter
#pragma unroll
    for (int r = 0; r < 4; ++r) {
      const int row = r * 32 + srow;
      const int scg = scl ^ (row & 7);
      __builtin_amdgcn_global_load_lds(
          (const __attribute__((address_space(1))) void*)(A + (size_t)(tm + row) * K + k0 + scg * 8),
          (__attribute__((address_space(3))) void*)(As + row * 64 + scl * 8), 16, 0, 0);
    }
    // B: convert prefetched f32 regs -> bf16, swizzled ds_write_b64
#pragma unroll
    for (int r = 0; r < 8; ++r) {
      const int row = r * 16 + br0;
      short4v sv;
      sv[0] = bf16_bits(breg[r].x); sv[1] = bf16_bits(breg[r].y);
      sv[2] = bf16_bits(breg[r].z); sv[3] = bf16_bits(breg[r].w);
      *(short4v*)&Bs[row * 64 + (((c16 >> 1) ^ (row & 7)) * 8) + (c16 & 1) * 4] = sv;
    }
    __syncthreads();
    if (k0 + 64 < K) {  // prefetch next B tile during MFMA phase
#pragma unroll
      for (int r = 0; r < 8; ++r)
        breg[r] = *(const float4*)(B + (size_t)(tn + r * 16 + br0) * K + k0 + 64 + c16 * 4);
    }

#pragma unroll
    for (int kk = 0; kk < 2; ++kk) {
      short8 af[4], bfr[4];
#pragma unroll
      for (int i = 0; i < 4; ++i) {
        const int ra = wm + i * 16 + lrow;
        const int rb = wn + i * 16 + lrow;
        af[i] = *(const short8*)&As[ra * 64 + (((kk * 4 + quad) ^ (ra & 7)) * 8)];
        bfr[i] = *(const short8*)&Bs[rb * 64 + (((kk * 4 + quad) ^ (rb & 7)) * 8)];
      }
#pragma unroll
      for (int i = 0; i < 4; ++i)
#pragma unroll
        for (int j = 0; j < 4; ++j)
          acc[i][j] = MFMA_BF16(af[i], bfr[j], acc[i][j]);
    }
  }

#pragma unroll
  for (int i = 0; i < 4; ++i)
#pragma unroll
    for (int j = 0; j < 4; ++j)
#pragma unroll
      for (int r = 0; r < 4; ++r) {
        const int row = tm + wm + i * 16 + quad * 4 + r;
        const int col = tn + wn + j * 16 + lrow;
        C[(size_t)row * ldc + col] = acc[i][j][r];
      }
}

// ---------------------------------------------------------------------------
// RoPE, in-place on the bf16 qkv buffer. qkv[b,s,f], f = (h/2)*768 + (h&1)*128
// + {q:0,k:256,v:512} + d. Rotate interleaved pairs of the first 32 dims of
// q,k. One thread per (b,s,h,q/k,pair): 4096*16*2*16 = 8192*256 threads.
// ---------------------------------------------------------------------------
__global__ void rope_kernel(bf16* __restrict__ qkv) {
  const int idx = blockIdx.x * 256 + threadIdx.x;
  const int i = idx & 15;  // freq/pair index
  int t = idx >> 4;
  const int qk = t & 1;
  t >>= 1;
  const int h = t & 15;
  t >>= 4;  // t = b*2048 + s
  const int s = t & 2047;
  bf16* p = qkv + (size_t)t * 6144 + (h >> 1) * 768 + (h & 1) * 128 + qk * 256 + 2 * i;
  const float x0 = __bfloat162float(p[0]);
  const float x1 = __bfloat162float(p[1]);
  const float inv = powf(10000.f, -(float)(2 * i) / 32.f);
  const float ang = (float)s * inv;
  float sn, cs;
  sincosf(ang, &sn, &cs);
  p[0] = __float2bfloat16(x0 * cs - x1 * sn);
  p[1] = __float2bfloat16(x1 * cs + x0 * sn);
}

// ---------------------------------------------------------------------------
// Flash attention. Grid (S/128, H, B). Block 256 = 4 waves; wave w owns q-rows
// [w*32, w*32+32). Q held in registers as A-frags; per k-block (64 keys):
// stage K (B-frag layout) and V transposed (B-frag layout) in LDS, S = Q K^T
// via MFMA, scale+causal mask, online softmax (16-lane shuffle reductions over
// the C-layout row groups), P -> LDS (A-frag layout), O += P V via MFMA.
// ---------------------------------------------------------------------------
__global__ __launch_bounds__(256) void attn_flash(
    const bf16* __restrict__ qkv, bf16* __restrict__ out) {
  __shared__ short Ks[16 * 64 * 8];  // [d/8][sk][8]
  __shared__ short Vs[8 * 128 * 8];  // [sk/8][d][8]   (V transposed)
  __shared__ short Ps[8 * 128 * 8];  // [sk/8][qrow][8]
  const int tid = threadIdx.x;
  const int wave = tid >> 6;
  const int lane = tid & 63;
  const int lrow = lane & 15;
  const int quad = lane >> 4;
  const int qb = blockIdx.x;
  const int h = blockIdx.y;
  const int b = blockIdx.z;
  const size_t SROW = 6144;
  const bf16* base = qkv + (size_t)b * 2048 * SROW;
  const int qoff = (h >> 1) * 768 + (h & 1) * 128;
  const int koff = qoff + 256;
  const int voff = qoff + 512;
  const float scale = 0.088388347648318447f;  // 1/sqrt(128)

  // Q A-frags: rows wave*32 + rt*16 + (lane&15), k(d) = ks*32 + quad*8 + j
  short8 qf[2][4];
#pragma unroll
  for (int rt = 0; rt < 2; ++rt) {
    const bf16* qp =
        base + (size_t)(qb * 128 + wave * 32 + rt * 16 + lrow) * SROW + qoff + quad * 8;
#pragma unroll
    for (int ks = 0; ks < 4; ++ks) qf[rt][ks] = *(const short8*)(qp + ks * 32);
  }

  floatx4 o[2][8] = {};
  float m_i[8], l_i[8];
#pragma unroll
  for (int i = 0; i < 8; ++i) {
    m_i[i] = -1e30f;
    l_i[i] = 0.f;
  }

  const int sr = tid >> 2;  // staging row 0..63
  const int sq = tid & 3;   // staging quarter of the 128-wide d strip

  const int kb_end = qb * 2 + 2;  // causal: only k-blocks overlapping tril
  for (int kb = 0; kb < kb_end; ++kb) {
    __syncthreads();  // all waves done reading Ks/Vs from previous iteration
    {
      // K tile: 64 rows x 128 d -> Ks[d/8][sk][8]
      const bf16* kp = base + (size_t)(kb * 64 + sr) * SROW + koff + sq * 32;
      short8 kv[4];
#pragma unroll
      for (int j = 0; j < 4; ++j) kv[j] = *(const short8*)(kp + j * 8);
#pragma unroll
      for (int j = 0; j < 4; ++j) *(short8*)&Ks[((sq * 4 + j) * 64 + sr) * 8] = kv[j];

      // V tile transposed: load V[sk][d0..d0+7] coalesced, scatter to Vs[sk/8][d][sk%8]
      const bf16* vp = base + (size_t)(kb * 64 + sr) * SROW + voff + sq * 8;
      const int so = (sr >> 3) * 128, si = sr & 7;
#pragma unroll
      for (int i = 0; i < 4; ++i) {
        short8 vv = *(const short8*)(vp + i * 32);
        const int d0 = sq * 8 + i * 32;
#pragma unroll
        for (int j = 0; j < 8; ++j) Vs[(so + d0 + j) * 8 + si] = vv[j];
      }
    }
    __syncthreads();

    // S = Q K^T  (rows: wave's 32 q-rows; cols: 64 keys)
    floatx4 sc[2][4] = {};
#pragma unroll
    for (int ks = 0; ks < 4; ++ks) {
      short8 bfr[4];
#pragma unroll
      for (int ct = 0; ct < 4; ++ct)
        bfr[ct] = *(const short8*)&Ks[((ks * 4 + quad) * 64 + ct * 16 + lrow) * 8];
#pragma unroll
      for (int rt = 0; rt < 2; ++rt)
#pragma unroll
        for (int ct = 0; ct < 4; ++ct)
          sc[rt][ct] = MFMA_BF16(qf[rt][ks], bfr[ct], sc[rt][ct]);
    }

    // scale + causal mask + online softmax (per C-layout row)
#pragma unroll
    for (int rt = 0; rt < 2; ++rt)
#pragma unroll
      for (int r = 0; r < 4; ++r) {
        const int idx = rt * 4 + r;
        const int row_g = qb * 128 + wave * 32 + rt * 16 + quad * 4 + r;
        float mx = -1e30f;
#pragma unroll
        for (int ct = 0; ct < 4; ++ct) {
          const int col_g = kb * 64 + ct * 16 + lrow;
          float v = sc[rt][ct][r] * scale;
          if (col_g > row_g) v = -1e9f;
          sc[rt][ct][r] = v;
          mx = fmaxf(mx, v);
        }
#pragma unroll
        for (int off = 1; off < 16; off <<= 1) mx = fmaxf(mx, __shfl_xor(mx, off, 64));
        const float mnew = fmaxf(m_i[idx], mx);
        const float alpha = __expf(m_i[idx] - mnew);
        m_i[idx] = mnew;
        float rs = 0.f;
#pragma unroll
        for (int ct = 0; ct < 4; ++ct) {
          const float p = __expf(sc[rt][ct][r] - mnew);
          sc[rt][ct][r] = p;
          rs += p;
        }
#pragma unroll
        for (int off = 1; off < 16; off <<= 1) rs += __shfl_xor(rs, off, 64);
        l_i[idx] = l_i[idx] * alpha + rs;
#pragma unroll
        for (int dt = 0; dt < 8; ++dt) o[rt][dt][r] *= alpha;
      }

    // P (bf16) -> LDS in A-frag layout
#pragma unroll
    for (int rt = 0; rt < 2; ++rt)
#pragma unroll
      for (int ct = 0; ct < 4; ++ct)
#pragma unroll
        for (int r = 0; r < 4; ++r) {
          const int row_l = wave * 32 + rt * 16 + quad * 4 + r;
          const int sk = ct * 16 + lrow;
          Ps[((sk >> 3) * 128 + row_l) * 8 + (sk & 7)] = bf16_bits(sc[rt][ct][r]);
        }
    __syncthreads();

    // O += P V
#pragma unroll
    for (int ks = 0; ks < 2; ++ks) {
      short8 af[2], bfr[8];
#pragma unroll
      for (int rt = 0; rt < 2; ++rt)
        af[rt] = *(const short8*)&Ps[((ks * 4 + quad) * 128 + wave * 32 + rt * 16 + lrow) * 8];
#pragma unroll
      for (int dt = 0; dt < 8; ++dt)
        bfr[dt] = *(const short8*)&Vs[((ks * 4 + quad) * 128 + dt * 16 + lrow) * 8];
#pragma unroll
      for (int rt = 0; rt < 2; ++rt)
#pragma unroll
        for (int dt = 0; dt < 8; ++dt)
          o[rt][dt] = MFMA_BF16(af[rt], bfr[dt], o[rt][dt]);
    }
  }

  // epilogue: O / l, store to (b, s, h*128 + d) bf16
#pragma unroll
  for (int rt = 0; rt < 2; ++rt)
#pragma unroll
    for (int dt = 0; dt < 8; ++dt)
#pragma unroll
      for (int r = 0; r < 4; ++r) {
        const int row = qb * 128 + wave * 32 + rt * 16 + quad * 4 + r;
        const int d = dt * 16 + lrow;
        const float val = o[rt][dt][r] / l_i[rt * 4 + r];
        out[((size_t)(b * 2048 + row)) * 2048 + h * 128 + d] = __float2bfloat16(val);
      }
}

// ---------------------------------------------------------------------------
// Workspace budget: EXACTLY 64 MiB of d_ws (the amount round 2 proved safe).
//   d_ws:  [0, 48 MiB)  qkv (4096 x 6144 bf16)
//          [48, 64 MiB) flex: W_qkv half (12 MiB) during GEMM1, then attnout
//   d_out: [0, 16 MiB)  hidden_bf16 scratch (dead before GEMM2 rewrites d_out)
// ---------------------------------------------------------------------------
extern "C" void kernel_launch(void* const* d_in, const int* in_sizes, int n_in,
                              void* d_out, int out_size, void* d_ws, size_t ws_size,
                              hipStream_t stream) {
  const float* hidden = (const float*)d_in[0];  // (2,2048,2048) f32
  const float* Wqkv = (const float*)d_in[1];    // (6144,2048)  f32
  const float* Wout = (const float*)d_in[2];    // (2048,2048)  f32
  float* outp = (float*)d_out;                  // (2,2048,2048) f32

  bf16* qkv = (bf16*)d_ws;                    // 25165824 elts = 48 MiB
  bf16* flex = qkv + (size_t)4096 * 6144;     // 16 MiB flex region
  bf16* hbf = (bf16*)d_out;                   // d_out scratch: 8388608 bf16 = 16 MiB

  // 0) hidden f32 -> bf16 into d_out scratch
  f32_to_bf16_kernel<<<4096, 256, 0, stream>>>(hidden, hbf, 1048576);

  // 1) qkv = hidden @ W_qkv^T in two N-halves (W_qkv converted half at a time)
  f32_to_bf16_kernel<<<3072, 256, 0, stream>>>(Wqkv, flex, 786432);
  gemm_bt_async<bf16><<<dim3(24, 32), 256, 0, stream>>>(hbf, flex, qkv, 6144, 2048);
  f32_to_bf16_kernel<<<3072, 256, 0, stream>>>(Wqkv + (size_t)3072 * 2048, flex, 786432);
  gemm_bt_async<bf16><<<dim3(24, 32), 256, 0, stream>>>(hbf, flex, qkv + 3072, 6144, 2048);

  // 2) RoPE in-place on q,k rot dims
  rope_kernel<<<8192, 256, 0, stream>>>(qkv);

  // 3) causal flash attention -> attnout (b,s,h*128+d) bf16, into flex
  bf16* attnout = flex;
  attn_flash<<<dim3(16, 16, 2), 256, 0, stream>>>(qkv, attnout);

  // 4) out = attnout @ W_out^T (W_out staged straight from f32) -> f32 d_out
  gemm_abf16_bf32<<<dim3(16, 32), 256, 0, stream>>>(attnout, Wout, outp, 2048, 2048);
}

// Round 7
// 441.654 us; speedup vs baseline: 1.8279x; 1.2344x over previous
//
#include <hip/hip_runtime.h>
#include <hip/hip_bf16.h>
#include <cstdint>
#include <cstddef>

using bf16 = __hip_bfloat16;
using short4v = __attribute__((ext_vector_type(4))) short;  // 4 bf16 (2 VGPRs)
using short8 = __attribute__((ext_vector_type(8))) short;   // 8 bf16 (4 VGPRs)
using floatx4 = __attribute__((ext_vector_type(4))) float;  // MFMA C/D frag

#define MFMA_BF16(A, B, C) __builtin_amdgcn_mfma_f32_16x16x32_bf16((A), (B), (C), 0, 0, 0)

__device__ inline short bf16_bits(float x) {
  bf16 v = __float2bfloat16(x);
  short r;
  __builtin_memcpy(&r, &v, 2);
  return r;
}

__device__ inline void store_c(bf16* p, float v) { *p = __float2bfloat16(v); }
__device__ inline void store_c(float* p, float v) { *p = v; }

// ---------------------------------------------------------------------------
// f32 -> bf16 bulk convert (RNE). 8 elements/thread, 16B stores.
// ---------------------------------------------------------------------------
__global__ __launch_bounds__(256) void f32_to_bf16_kernel(
    const float* __restrict__ src, bf16* __restrict__ dst, int n8) {
  const int i = blockIdx.x * 256 + threadIdx.x;
  if (i >= n8) return;
  const float4 a = ((const float4*)src)[2 * i];
  const float4 b = ((const float4*)src)[2 * i + 1];
  short8 r;
  r[0] = bf16_bits(a.x); r[1] = bf16_bits(a.y); r[2] = bf16_bits(a.z); r[3] = bf16_bits(a.w);
  r[4] = bf16_bits(b.x); r[5] = bf16_bits(b.y); r[6] = bf16_bits(b.z); r[7] = bf16_bits(b.w);
  *(short8*)(dst + (size_t)i * 8) = r;
}

// ---------------------------------------------------------------------------
// GEMM (m97 structure): C[m,n] = sum_k A[m,k]*B[n,k], A,B row-major bf16,
// row stride K; C row-major stride ldc. Tile 128x128, BK=64, 4 waves (2x2).
// global_load_lds width=16 staging with XOR chunk swizzle.
// ---------------------------------------------------------------------------
template <typename TC>
__global__ __launch_bounds__(256) void gemm_bt_async(
    const bf16* __restrict__ A, const bf16* __restrict__ B, TC* __restrict__ C,
    int ldc, int K) {
  __shared__ bf16 As[128 * 64];
  __shared__ bf16 Bs[128 * 64];
  const int tid = threadIdx.x;
  const int lane = tid & 63;
  const int wave = tid >> 6;
  const int lrow = lane & 15;
  const int quad = lane >> 4;
  const int wm = (wave >> 1) * 64;
  const int wn = (wave & 1) * 64;
  const int tm = blockIdx.y * 128;
  const int tn = blockIdx.x * 128;

  const int srow = tid >> 3;
  const int scl = tid & 7;

  floatx4 acc[4][4] = {};

  for (int k0 = 0; k0 < K; k0 += 64) {
    __syncthreads();
#pragma unroll
    for (int r = 0; r < 4; ++r) {
      const int row = r * 32 + srow;
      const int scg = scl ^ (row & 7);
      __builtin_amdgcn_global_load_lds(
          (const __attribute__((address_space(1))) void*)(A + (size_t)(tm + row) * K + k0 + scg * 8),
          (__attribute__((address_space(3))) void*)(As + row * 64 + scl * 8), 16, 0, 0);
    }
#pragma unroll
    for (int r = 0; r < 4; ++r) {
      const int row = r * 32 + srow;
      const int scg = scl ^ (row & 7);
      __builtin_amdgcn_global_load_lds(
          (const __attribute__((address_space(1))) void*)(B + (size_t)(tn + row) * K + k0 + scg * 8),
          (__attribute__((address_space(3))) void*)(Bs + row * 64 + scl * 8), 16, 0, 0);
    }
    __syncthreads();

#pragma unroll
    for (int kk = 0; kk < 2; ++kk) {
      short8 af[4], bfr[4];
#pragma unroll
      for (int i = 0; i < 4; ++i) {
        const int ra = wm + i * 16 + lrow;
        const int rb = wn + i * 16 + lrow;
        af[i] = *(const short8*)&As[ra * 64 + (((kk * 4 + quad) ^ (ra & 7)) * 8)];
        bfr[i] = *(const short8*)&Bs[rb * 64 + (((kk * 4 + quad) ^ (rb & 7)) * 8)];
      }
#pragma unroll
      for (int i = 0; i < 4; ++i)
#pragma unroll
        for (int j = 0; j < 4; ++j)
          acc[i][j] = MFMA_BF16(af[i], bfr[j], acc[i][j]);
    }
  }

#pragma unroll
  for (int i = 0; i < 4; ++i)
#pragma unroll
    for (int j = 0; j < 4; ++j)
#pragma unroll
      for (int r = 0; r < 4; ++r) {
        const int row = tm + wm + i * 16 + quad * 4 + r;
        const int col = tn + wn + j * 16 + lrow;
        store_c(&C[(size_t)row * ldc + col], acc[i][j][r]);
      }
}

// ---------------------------------------------------------------------------
// Mixed GEMM for the out-projection: A bf16 via global_load_lds; B f32 weight
// via register prefetch + convert + swizzled ds_write. C f32.
// ---------------------------------------------------------------------------
__global__ __launch_bounds__(256) void gemm_abf16_bf32(
    const bf16* __restrict__ A, const float* __restrict__ B, float* __restrict__ C,
    int ldc, int K) {
  __shared__ bf16 As[128 * 64];
  __shared__ bf16 Bs[128 * 64];
  const int tid = threadIdx.x;
  const int lane = tid & 63;
  const int wave = tid >> 6;
  const int lrow = lane & 15;
  const int quad = lane >> 4;
  const int wm = (wave >> 1) * 64;
  const int wn = (wave & 1) * 64;
  const int tm = blockIdx.y * 128;
  const int tn = blockIdx.x * 128;

  const int srow = tid >> 3;
  const int scl = tid & 7;
  const int c16 = tid & 15;
  const int br0 = tid >> 4;

  floatx4 acc[4][4] = {};
  float4 breg[8];
#pragma unroll
  for (int r = 0; r < 8; ++r)
    breg[r] = *(const float4*)(B + (size_t)(tn + r * 16 + br0) * K + c16 * 4);

  for (int k0 = 0; k0 < K; k0 += 64) {
    __syncthreads();
#pragma unroll
    for (int r = 0; r < 4; ++r) {
      const int row = r * 32 + srow;
      const int scg = scl ^ (row & 7);
      __builtin_amdgcn_global_load_lds(
          (const __attribute__((address_space(1))) void*)(A + (size_t)(tm + row) * K + k0 + scg * 8),
          (__attribute__((address_space(3))) void*)(As + row * 64 + scl * 8), 16, 0, 0);
    }
#pragma unroll
    for (int r = 0; r < 8; ++r) {
      const int row = r * 16 + br0;
      short4v sv;
      sv[0] = bf16_bits(breg[r].x); sv[1] = bf16_bits(breg[r].y);
      sv[2] = bf16_bits(breg[r].z); sv[3] = bf16_bits(breg[r].w);
      *(short4v*)&Bs[row * 64 + (((c16 >> 1) ^ (row & 7)) * 8) + (c16 & 1) * 4] = sv;
    }
    __syncthreads();
    if (k0 + 64 < K) {
#pragma unroll
      for (int r = 0; r < 8; ++r)
        breg[r] = *(const float4*)(B + (size_t)(tn + r * 16 + br0) * K + k0 + 64 + c16 * 4);
    }

#pragma unroll
    for (int kk = 0; kk < 2; ++kk) {
      short8 af[4], bfr[4];
#pragma unroll
      for (int i = 0; i < 4; ++i) {
        const int ra = wm + i * 16 + lrow;
        const int rb = wn + i * 16 + lrow;
        af[i] = *(const short8*)&As[ra * 64 + (((kk * 4 + quad) ^ (ra & 7)) * 8)];
        bfr[i] = *(const short8*)&Bs[rb * 64 + (((kk * 4 + quad) ^ (rb & 7)) * 8)];
      }
#pragma unroll
      for (int i = 0; i < 4; ++i)
#pragma unroll
        for (int j = 0; j < 4; ++j)
          acc[i][j] = MFMA_BF16(af[i], bfr[j], acc[i][j]);
    }
  }

#pragma unroll
  for (int i = 0; i < 4; ++i)
#pragma unroll
    for (int j = 0; j < 4; ++j)
#pragma unroll
      for (int r = 0; r < 4; ++r) {
        const int row = tm + wm + i * 16 + quad * 4 + r;
        const int col = tn + wn + j * 16 + lrow;
        C[(size_t)row * ldc + col] = acc[i][j][r];
      }
}

// ---------------------------------------------------------------------------
// RoPE, in-place on bf16 qkv. One thread per (b,s,h,q/k,pair).
// ---------------------------------------------------------------------------
__global__ void rope_kernel(bf16* __restrict__ qkv) {
  const int idx = blockIdx.x * 256 + threadIdx.x;
  const int i = idx & 15;
  int t = idx >> 4;
  const int qk = t & 1;
  t >>= 1;
  const int h = t & 15;
  t >>= 4;
  const int s = t & 2047;
  bf16* p = qkv + (size_t)t * 6144 + (h >> 1) * 768 + (h & 1) * 128 + qk * 256 + 2 * i;
  const float x0 = __bfloat162float(p[0]);
  const float x1 = __bfloat162float(p[1]);
  const float inv = powf(10000.f, -(float)(2 * i) / 32.f);
  const float ang = (float)s * inv;
  float sn, cs;
  sincosf(ang, &sn, &cs);
  p[0] = __float2bfloat16(x0 * cs - x1 * sn);
  p[1] = __float2bfloat16(x1 * cs + x0 * sn);
}

// ---------------------------------------------------------------------------
// Flash attention — round-4 PROVEN internals + causal work pairing.
// Grid (8, H, B): block processes q-tile blockIdx.x then q-tile 15-blockIdx.x
// sequentially -> every block does exactly 34 k-iterations (balanced makespan,
// 256 blocks = 1/CU). Internals identical to the passing round-4 kernel:
// wave w owns q-rows [qb*128 + w*32, +32); per 64-key block: register-staged
// K (B-frag layout) and V-transposed in LDS; S = Q K^T via MFMA; scale +
// causal mask + online softmax (16-lane shuffle reductions over C-layout
// rows); P -> LDS (A-frag layout, barrier); O += P V via MFMA.
// ---------------------------------------------------------------------------
__global__ __launch_bounds__(256) void attn_flash_pair(
    const bf16* __restrict__ qkv, bf16* __restrict__ out) {
  __shared__ short Ks[16 * 64 * 8];  // [d/8][sk][8]
  __shared__ short Vs[8 * 128 * 8];  // [sk/8][d][8]   (V transposed)
  __shared__ short Ps[8 * 128 * 8];  // [sk/8][qrow][8]
  const int tid = threadIdx.x;
  const int wave = tid >> 6;
  const int lane = tid & 63;
  const int lrow = lane & 15;
  const int quad = lane >> 4;
  const int h = blockIdx.y;
  const int b = blockIdx.z;
  const size_t SROW = 6144;
  const bf16* base = qkv + (size_t)b * 2048 * SROW;
  const int qoff = (h >> 1) * 768 + (h & 1) * 128;
  const int koff = qoff + 256;
  const int voff = qoff + 512;
  const float scale = 0.088388347648318447f;  // 1/sqrt(128)

  const int sr = tid >> 2;  // staging row 0..63
  const int sq = tid & 3;   // staging quarter of the 128-wide d strip

  for (int phase = 0; phase < 2; ++phase) {
    const int qb = phase ? (15 - (int)blockIdx.x) : (int)blockIdx.x;

    // Q A-frags: rows qb*128 + wave*32 + rt*16 + lrow, d = ks*32 + quad*8 + j
    short8 qf[2][4];
#pragma unroll
    for (int rt = 0; rt < 2; ++rt) {
      const bf16* qp =
          base + (size_t)(qb * 128 + wave * 32 + rt * 16 + lrow) * SROW + qoff + quad * 8;
#pragma unroll
      for (int ks = 0; ks < 4; ++ks) qf[rt][ks] = *(const short8*)(qp + ks * 32);
    }

    floatx4 o[2][8] = {};
    float m_i[8], l_i[8];
#pragma unroll
    for (int i = 0; i < 8; ++i) {
      m_i[i] = -1e30f;
      l_i[i] = 0.f;
    }

    const int kb_end = qb * 2 + 2;  // causal: only k-blocks overlapping tril
    for (int kb = 0; kb < kb_end; ++kb) {
      __syncthreads();  // all waves done reading Ks/Vs (prev iter or prev phase)
      {
        // K tile: 64 rows x 128 d -> Ks[d/8][sk][8]
        const bf16* kp = base + (size_t)(kb * 64 + sr) * SROW + koff + sq * 32;
        short8 kv[4];
#pragma unroll
        for (int j = 0; j < 4; ++j) kv[j] = *(const short8*)(kp + j * 8);
#pragma unroll
        for (int j = 0; j < 4; ++j) *(short8*)&Ks[((sq * 4 + j) * 64 + sr) * 8] = kv[j];

        // V tile transposed: load V[sk][d0..d0+7] coalesced, scatter to Vs[sk/8][d][sk%8]
        const bf16* vp = base + (size_t)(kb * 64 + sr) * SROW + voff + sq * 8;
        const int so = (sr >> 3) * 128, si = sr & 7;
#pragma unroll
        for (int i = 0; i < 4; ++i) {
          short8 vv = *(const short8*)(vp + i * 32);
          const int d0 = sq * 8 + i * 32;
#pragma unroll
          for (int j = 0; j < 8; ++j) Vs[(so + d0 + j) * 8 + si] = vv[j];
        }
      }
      __syncthreads();

      // S = Q K^T  (rows: wave's 32 q-rows; cols: 64 keys)
      floatx4 sc[2][4] = {};
#pragma unroll
      for (int ks = 0; ks < 4; ++ks) {
        short8 bfr[4];
#pragma unroll
        for (int ct = 0; ct < 4; ++ct)
          bfr[ct] = *(const short8*)&Ks[((ks * 4 + quad) * 64 + ct * 16 + lrow) * 8];
#pragma unroll
        for (int rt = 0; rt < 2; ++rt)
#pragma unroll
          for (int ct = 0; ct < 4; ++ct)
            sc[rt][ct] = MFMA_BF16(qf[rt][ks], bfr[ct], sc[rt][ct]);
      }

      // scale + causal mask + online softmax (per C-layout row)
#pragma unroll
      for (int rt = 0; rt < 2; ++rt)
#pragma unroll
        for (int r = 0; r < 4; ++r) {
          const int idx = rt * 4 + r;
          const int row_g = qb * 128 + wave * 32 + rt * 16 + quad * 4 + r;
          float mx = -1e30f;
#pragma unroll
          for (int ct = 0; ct < 4; ++ct) {
            const int col_g = kb * 64 + ct * 16 + lrow;
            float v = sc[rt][ct][r] * scale;
            if (col_g > row_g) v = -1e9f;
            sc[rt][ct][r] = v;
            mx = fmaxf(mx, v);
          }
#pragma unroll
          for (int off = 1; off < 16; off <<= 1) mx = fmaxf(mx, __shfl_xor(mx, off, 64));
          const float mnew = fmaxf(m_i[idx], mx);
          const float alpha = __expf(m_i[idx] - mnew);
          m_i[idx] = mnew;
          float rs = 0.f;
#pragma unroll
          for (int ct = 0; ct < 4; ++ct) {
            const float p = __expf(sc[rt][ct][r] - mnew);
            sc[rt][ct][r] = p;
            rs += p;
          }
#pragma unroll
          for (int off = 1; off < 16; off <<= 1) rs += __shfl_xor(rs, off, 64);
          l_i[idx] = l_i[idx] * alpha + rs;
#pragma unroll
          for (int dt = 0; dt < 8; ++dt) o[rt][dt][r] *= alpha;
        }

      // P (bf16) -> LDS in A-frag layout
#pragma unroll
      for (int rt = 0; rt < 2; ++rt)
#pragma unroll
        for (int ct = 0; ct < 4; ++ct)
#pragma unroll
          for (int r = 0; r < 4; ++r) {
            const int row_l = wave * 32 + rt * 16 + quad * 4 + r;
            const int sk = ct * 16 + lrow;
            Ps[((sk >> 3) * 128 + row_l) * 8 + (sk & 7)] = bf16_bits(sc[rt][ct][r]);
          }
      __syncthreads();

      // O += P V
#pragma unroll
      for (int ks = 0; ks < 2; ++ks) {
        short8 af[2], bfr[8];
#pragma unroll
        for (int rt = 0; rt < 2; ++rt)
          af[rt] = *(const short8*)&Ps[((ks * 4 + quad) * 128 + wave * 32 + rt * 16 + lrow) * 8];
#pragma unroll
        for (int dt = 0; dt < 8; ++dt)
          bfr[dt] = *(const short8*)&Vs[((ks * 4 + quad) * 128 + dt * 16 + lrow) * 8];
#pragma unroll
        for (int rt = 0; rt < 2; ++rt)
#pragma unroll
          for (int dt = 0; dt < 8; ++dt)
            o[rt][dt] = MFMA_BF16(af[rt], bfr[dt], o[rt][dt]);
      }
    }

    // epilogue: O / l, store to (b, s, h*128 + d) bf16
#pragma unroll
    for (int rt = 0; rt < 2; ++rt)
#pragma unroll
      for (int dt = 0; dt < 8; ++dt)
#pragma unroll
        for (int r = 0; r < 4; ++r) {
          const int row = qb * 128 + wave * 32 + rt * 16 + quad * 4 + r;
          const int d = dt * 16 + lrow;
          const float val = o[rt][dt][r] / l_i[rt * 4 + r];
          out[((size_t)(b * 2048 + row)) * 2048 + h * 128 + d] = __float2bfloat16(val);
        }
  }
}

// ---------------------------------------------------------------------------
// Workspace budget: 64 MiB of d_ws (round-2-proven safe).
//   d_ws:  [0, 48 MiB)  qkv; [48, 64 MiB) flex: W_qkv half, then attnout
//   d_out: [0, 16 MiB)  hidden_bf16 scratch (dead before GEMM2 rewrites)
// ---------------------------------------------------------------------------
extern "C" void kernel_launch(void* const* d_in, const int* in_sizes, int n_in,
                              void* d_out, int out_size, void* d_ws, size_t ws_size,
                              hipStream_t stream) {
  const float* hidden = (const float*)d_in[0];  // (2,2048,2048) f32
  const float* Wqkv = (const float*)d_in[1];    // (6144,2048)  f32
  const float* Wout = (const float*)d_in[2];    // (2048,2048)  f32
  float* outp = (float*)d_out;                  // (2,2048,2048) f32

  bf16* qkv = (bf16*)d_ws;                    // 48 MiB
  bf16* flex = qkv + (size_t)4096 * 6144;     // 16 MiB flex
  bf16* hbf = (bf16*)d_out;                   // d_out scratch, 16 MiB

  f32_to_bf16_kernel<<<4096, 256, 0, stream>>>(hidden, hbf, 1048576);

  f32_to_bf16_kernel<<<3072, 256, 0, stream>>>(Wqkv, flex, 786432);
  gemm_bt_async<bf16><<<dim3(24, 32), 256, 0, stream>>>(hbf, flex, qkv, 6144, 2048);
  f32_to_bf16_kernel<<<3072, 256, 0, stream>>>(Wqkv + (size_t)3072 * 2048, flex, 786432);
  gemm_bt_async<bf16><<<dim3(24, 32), 256, 0, stream>>>(hbf, flex, qkv + 3072, 6144, 2048);

  rope_kernel<<<8192, 256, 0, stream>>>(qkv);

  bf16* attnout = flex;
  attn_flash_pair<<<dim3(8, 16, 2), 256, 0, stream>>>(qkv, attnout);

  gemm_abf16_bf32<<<dim3(16, 32), 256, 0, stream>>>(attnout, Wout, outp, 2048, 2048);
}